// Round 8
// baseline (341.247 us; speedup 1.0000x reference)
//
#include <hip/hip_runtime.h>

#define LEAKY 0.2f
#define NBSHIFT 8          // 256 nodes per bucket
#define TILE 4096          // edges per multisplit block

typedef __attribute__((ext_vector_type(8))) short  bfrag;   // 8 bf16 = 4 VGPR
typedef __attribute__((ext_vector_type(4))) float  f32x4;

__device__ __forceinline__ unsigned bf16rne(float v) {
    unsigned u = __float_as_uint(v);
    return (u + 0x7FFF + ((u >> 16) & 1)) >> 16;
}
__device__ __forceinline__ float bf16tof(unsigned b) { return __uint_as_float(b << 16); }

// pure-VALU DPP 16-lane-group sum (no ds_swizzle/lgkm waits)
#define DPPADD(p, ctrl)                                                       \
    p += __int_as_float(__builtin_amdgcn_mov_dpp(__float_as_int(p), ctrl,     \
                                                 0xF, 0xF, true))
__device__ __forceinline__ float rowsum16(float p) {
    DPPADD(p, 0xB1);   // quad_perm [1,0,3,2]  = xor 1
    DPPADD(p, 0x4E);   // quad_perm [2,3,0,1]  = xor 2
    DPPADD(p, 0x124);  // row_ror:4
    DPPADD(p, 0x128);  // row_ror:8
    return p;
}

// ---------------- CSR build: bucketed multisplit ----------------

__global__ __launch_bounds__(256) void bucket_hist(const int* __restrict__ dst,
                                                   int* __restrict__ bcnt, int E, int nb) {
    __shared__ int h[256];
    h[threadIdx.x] = 0;
    __syncthreads();
    for (int e = blockIdx.x * 256 + threadIdx.x; e < E; e += gridDim.x * 256)
        atomicAdd(&h[dst[e] >> NBSHIFT], 1);
    __syncthreads();
    int v = h[threadIdx.x];
    if (threadIdx.x < nb && v) atomicAdd(&bcnt[threadIdx.x], v);
}

__global__ __launch_bounds__(256) void bucket_scan(const int* __restrict__ bcnt,
                                                   int* __restrict__ bbase,
                                                   int* __restrict__ gwoff,
                                                   int* __restrict__ rowptr,
                                                   int E, int nb, int n) {
    __shared__ int s[256];
    const int t = threadIdx.x;
    int v = (t < nb) ? bcnt[t] : 0;
    s[t] = v;
    __syncthreads();
    for (int off = 1; off < 256; off <<= 1) {
        int a = (t >= off) ? s[t - off] : 0;
        __syncthreads();
        s[t] += a;
        __syncthreads();
    }
    int excl = s[t] - v;
    if (t < nb) { bbase[t] = excl; gwoff[t] = excl; }
    if (t == 0) { bbase[nb] = E; rowptr[n] = E; }
}

// Tile-wise multisplit: stage TILE edges in LDS sorted by bucket, reserve
// per-bucket global chunks, flush coalesced runs (avg ~21 edges = 168B).
__global__ __launch_bounds__(256) void multisplit(const int* __restrict__ src,
                                                  const int* __restrict__ dst,
                                                  int* __restrict__ gwoff,
                                                  int2* __restrict__ pairs, int E, int nb) {
    __shared__ int hist[256], lofs[256], gb[256];
    __shared__ int2 st[TILE];
    const int t = threadIdx.x;
    const int tile0 = blockIdx.x * TILE;
    const int tend = min(tile0 + TILE, E);
    hist[t] = 0;
    __syncthreads();
    for (int e = tile0 + t; e < tend; e += 256)
        atomicAdd(&hist[dst[e] >> NBSHIFT], 1);
    __syncthreads();
    int v = hist[t];
    lofs[t] = v;
    __syncthreads();
    for (int off = 1; off < 256; off <<= 1) {
        int a = (t >= off) ? lofs[t - off] : 0;
        __syncthreads();
        lofs[t] += a;
        __syncthreads();
    }
    int excl = lofs[t] - v;
    __syncthreads();
    lofs[t] = excl;
    if (t < nb && v > 0) gb[t] = atomicAdd(&gwoff[t], v);
    hist[t] = 0;
    __syncthreads();
    for (int e = tile0 + t; e < tend; e += 256) {
        int d = dst[e];
        int b = d >> NBSHIFT;
        int r = atomicAdd(&hist[b], 1);
        st[lofs[b] + r] = make_int2(src[e], d);
    }
    __syncthreads();
    const int total = tend - tile0;
    for (int i = t; i < total; i += 256) {
        int2 p = st[i];
        int b = p.y >> NBSHIFT;
        pairs[gb[b] + (i - lofs[b])] = p;
    }
}

// One block per bucket: LDS counting sort over the 256-node range ->
// rowptr + ssrc (writes land in a 16KB single-block region: L2 merges lines).
__global__ __launch_bounds__(256) void bucket_sort(const int2* __restrict__ pairs,
                                                   const int* __restrict__ bbase,
                                                   int* __restrict__ rowptr,
                                                   int* __restrict__ ssrc, int n) {
    __shared__ int hist[256], ofs[256];
    const int b = blockIdx.x, t = threadIdx.x;
    const int base = b << NBSHIFT;
    const int pbeg = bbase[b], pend = bbase[b + 1];
    hist[t] = 0;
    __syncthreads();
    for (int i = pbeg + t; i < pend; i += 256)
        atomicAdd(&hist[pairs[i].y - base], 1);
    __syncthreads();
    int v = hist[t];
    ofs[t] = v;
    __syncthreads();
    for (int off = 1; off < 256; off <<= 1) {
        int a = (t >= off) ? ofs[t - off] : 0;
        __syncthreads();
        ofs[t] += a;
        __syncthreads();
    }
    int excl = ofs[t] - v;
    __syncthreads();
    ofs[t] = excl;
    const int node = base + t;
    if (node < n) rowptr[node] = pbeg + excl;
    __syncthreads();
    for (int i = pbeg + t; i < pend; i += 256) {
        int2 p = pairs[i];
        int pos = atomicAdd(&ofs[p.y - base], 1);
        ssrc[pbeg + pos] = p.x;
    }
}

// ---------------- prep: split x into bf16 hi/lo planes ----------------

__global__ void split_x(const float* __restrict__ x, ushort* __restrict__ xhi,
                        ushort* __restrict__ xlo, int total4) {
    int i = blockIdx.x * blockDim.x + threadIdx.x;
    if (i >= total4) return;
    float4 v = reinterpret_cast<const float4*>(x)[i];
    ushort4 h, l;
    float* vp = &v.x;
    ushort* hp = &h.x;
    ushort* lp = &l.x;
#pragma unroll
    for (int j = 0; j < 4; ++j) {
        unsigned hb = bf16rne(vp[j]);
        hp[j] = (ushort)hb;
        lp[j] = (ushort)bf16rne(vp[j] - bf16tof(hb));
    }
    reinterpret_cast<ushort4*>(xhi)[i] = h;
    reinterpret_cast<ushort4*>(xlo)[i] = l;
}

// ---------------- prep: pack [Wl|Wr] into MFMA B-fragment order ----------------
// b-frag (s = k/32, f = col/16): lane l, elem j holds W[s*32 + (l>>4)*8 + j][f*16 + (l&15)]
// packed linearly: pos = ((s*16 + f)*64 + lane)*8 + j   (ushort)

__global__ void pack_W(const float* __restrict__ Wl, const float* __restrict__ Wr,
                       ushort* __restrict__ Bhi, ushort* __restrict__ Blo, int K) {
    int tid = blockIdx.x * blockDim.x + threadIdx.x;
    if (tid >= K * 256) return;
    int k = tid >> 8;
    int c = tid & 255;
    float w = (c < 128) ? Wl[k * 128 + c] : Wr[k * 128 + (c - 128)];
    int s = k >> 5, kin = k & 31, kgrp = kin >> 3, j = kin & 7;
    int f = c >> 4, cin = c & 15;
    int lane = kgrp * 16 + cin;
    size_t pos = ((size_t)(s * 16 + f) * 64 + lane) * 8 + j;
    unsigned hb = bf16rne(w);
    Bhi[pos] = (ushort)hb;
    Blo[pos] = (ushort)bf16rne(w - bf16tof(hb));
}

// ---------------- MFMA GEMM: [xl|xr] = A @ [Wl|Wr] + [bl|br] ----------------
// grid = (row-tiles, 2 N-halves). Block = 4 waves, tile 64 rows x 128 cols.
// B staged in LDS (32KB -> 4 blocks/CU), read via ds_read_b128.
// Split-bf16: acc += alo*bhi + ahi*blo + ahi*bhi.
// half 0 writes xl as a HEAD-MAJOR bf16 plane [4][n][32] (each head slice =
// 3.2MB, fits per-XCD L2 for gat_agg's head passes); half 1 writes xr f32.

template<int K>
__global__ __launch_bounds__(256) void gemm_mfma(
    const ushort* __restrict__ Ahi, const ushort* __restrict__ Alo,
    const ushort* __restrict__ Bhi, const ushort* __restrict__ Blo,
    const float* __restrict__ bl, const float* __restrict__ br,
    ushort* __restrict__ xlb, float* __restrict__ xr, int n)
{
    __shared__ ushort BshH[2 * 8 * 64 * 8];   // [ss][fl][lane][j] 16KB
    __shared__ ushort BshL[2 * 8 * 64 * 8];   // 16KB
    const int t = threadIdx.x;
    const int w = t >> 6;
    const int lane = t & 63;
    const int half = blockIdx.y;              // 0 -> xl cols, 1 -> xr cols
    const int r0 = blockIdx.x * 64 + w * 16;
    const int rl = lane & 15;
    const int kg = lane >> 4;
    int arow = r0 + rl; if (arow >= n) arow = 0;   // clamp loads; stores guarded

    const float4* __restrict__ gH = reinterpret_cast<const float4*>(Bhi);
    const float4* __restrict__ gL = reinterpret_cast<const float4*>(Blo);
    float4* __restrict__ sH = reinterpret_cast<float4*>(BshH);
    float4* __restrict__ sL = reinterpret_cast<float4*>(BshL);

    f32x4 acc[8];
#pragma unroll
    for (int f = 0; f < 8; ++f) acc[f] = (f32x4){0.f, 0.f, 0.f, 0.f};

#pragma unroll
    for (int sg = 0; sg < K / 64; ++sg) {
        if (sg) __syncthreads();
        // stage s = 2sg, 2sg+1 for this block's 8 col-frags
#pragma unroll
        for (int i = t; i < 1024; i += 256) {
            int ss = i >> 9, fl = (i >> 6) & 7, ln = i & 63;
            int gidx = ((2 * sg + ss) * 16 + half * 8 + fl) * 64 + ln;
            sH[i] = gH[gidx];
            sL[i] = gL[gidx];
        }
        __syncthreads();

#pragma unroll
        for (int ss = 0; ss < 2; ++ss) {
            const int s = 2 * sg + ss;
            const size_t ao = (size_t)arow * K + s * 32 + kg * 8;
            bfrag ahi = *reinterpret_cast<const bfrag*>(&Ahi[ao]);
            bfrag alo = *reinterpret_cast<const bfrag*>(&Alo[ao]);
#pragma unroll
            for (int fl = 0; fl < 8; ++fl) {
                const int lofs = ((ss * 8 + fl) * 64 + lane) * 8;
                bfrag bhi = *reinterpret_cast<const bfrag*>(&BshH[lofs]);
                bfrag blo = *reinterpret_cast<const bfrag*>(&BshL[lofs]);
                acc[fl] = __builtin_amdgcn_mfma_f32_16x16x32_bf16(alo, bhi, acc[fl], 0, 0, 0);
                acc[fl] = __builtin_amdgcn_mfma_f32_16x16x32_bf16(ahi, blo, acc[fl], 0, 0, 0);
                acc[fl] = __builtin_amdgcn_mfma_f32_16x16x32_bf16(ahi, bhi, acc[fl], 0, 0, 0);
            }
        }
    }

    // D layout: col = fl*16 + (lane&15), row = r0 + (lane>>4)*4 + j
    const int cin = lane & 15;
    const float* __restrict__ bias_ = half ? br : bl;
#pragma unroll
    for (int fl = 0; fl < 8; ++fl) {
        const int cc = fl * 16 + cin;
        const float bv = bias_[cc];
#pragma unroll
        for (int j = 0; j < 4; ++j) {
            const int rr = r0 + kg * 4 + j;
            if (rr < n) {
                const float v = acc[fl][j] + bv;
                if (half) xr[(size_t)rr * 128 + cc] = v;
                else      xlb[((size_t)(cc >> 5) * n + rr) * 32 + (cc & 31)] =
                              (ushort)bf16rne(v);
            }
        }
    }
}

// ---------------- fused per-destination GATv2 aggregation ----------------
// HEAD-SPLIT: grid = nodeblks * 4 heads, head = blockIdx.x / nodeblks so all
// of head h's blocks dispatch before head h+1 -> the active gather plane
// ([n][32] bf16 = 3.2MB) is per-XCD-L2-resident. One node per wave; 4 edges
// per wave-pass (slot = lane>>4, 16 lanes/edge, lane owns 2 channels as uint,
// 64B/edge gather). Score = rowsum16 DPP; slots combined via shfl_xor at end.

template<int OUTMODE>
__global__ __launch_bounds__(256) void gat_agg(
    const ushort* __restrict__ xlb,    // head-major [4][n][32] bf16
    const float* __restrict__ xr,      // [n][128] f32
    const float* __restrict__ att, const float* __restrict__ bias,
    const int* __restrict__ rowptr, const int* __restrict__ ssrc,
    float* __restrict__ out, ushort* __restrict__ ohi, ushort* __restrict__ olo,
    int n, int nodeblks)
{
    const int head = blockIdx.x / nodeblks;
    const int nblk = blockIdx.x - head * nodeblks;
    const int node = nblk * 4 + (threadIdx.x >> 6);
    if (node >= n) return;
    const int lane = threadIdx.x & 63;
    const int slot = lane >> 4;    // edge slot 0..3
    const int m = lane & 15;       // channel-pair within head

    const uint* __restrict__ xlu =
        reinterpret_cast<const uint*>(xlb) + (size_t)head * n * 16;
    const float2 a2  = *reinterpret_cast<const float2*>(&att[head * 32 + m * 2]);
    const float2 xrv = *reinterpret_cast<const float2*>(
        &xr[(size_t)node * 128 + head * 32 + m * 2]);

    float den = 0.f;
    float2 acc = make_float2(0.f, 0.f);

#define PAIR(s, MSK)                                                  \
    {                                                                 \
        const uint u = xlu[(size_t)(s) * 16 + m];                     \
        const float x0 = __uint_as_float(u << 16);                    \
        const float x1 = __uint_as_float(u & 0xFFFF0000u);            \
        float e0 = x0 + xrv.x, e1 = x1 + xrv.y;                       \
        e0 = e0 > 0.f ? e0 : LEAKY * e0;                              \
        e1 = e1 > 0.f ? e1 : LEAKY * e1;                              \
        float p = rowsum16(e0 * a2.x + e1 * a2.y);                    \
        float ex = __expf(p) MSK;                                     \
        den += ex;                                                    \
        acc.x += ex * x0;                                             \
        acc.y += ex * x1;                                             \
    }

    int i = rowptr[node];
    const int end = rowptr[node + 1];

    // pass 0: slot 0 = self loop, slots 1..3 = first up-to-3 real edges
    {
        const int nv = min(end - i, 3);
        const int s = (slot == 0) ? node
                                  : ((slot <= nv) ? ssrc[i + slot - 1] : node);
        const float msk = (slot <= nv) ? 1.f : 0.f;
        PAIR(s, * msk);
        i += nv;
    }

    for (; i + 4 <= end; i += 4) {
        const int s = ssrc[i + slot];
        PAIR(s, );
    }
    {
        const int rem = end - i;
        if (rem > 0) {
            const int s = (slot < rem) ? ssrc[i + slot] : node;
            const float msk = (slot < rem) ? 1.f : 0.f;
            PAIR(s, * msk);
        }
    }
#undef PAIR

    // combine the 4 edge slots
    den   += __shfl_xor(den,   16); den   += __shfl_xor(den,   32);
    acc.x += __shfl_xor(acc.x, 16); acc.x += __shfl_xor(acc.x, 32);
    acc.y += __shfl_xor(acc.y, 16); acc.y += __shfl_xor(acc.y, 32);

    if (lane < 16) {
        const float2 b2 = *reinterpret_cast<const float2*>(&bias[head * 32 + m * 2]);
        const float r = 1.f / den;
        const float o0 = fmaxf(acc.x * r + b2.x, 0.f);
        const float o1 = fmaxf(acc.y * r + b2.y, 0.f);
        const size_t oidx = (size_t)node * 128 + head * 32 + m * 2;
        if (OUTMODE == 0) {
            *reinterpret_cast<float2*>(&out[oidx]) = make_float2(o0, o1);
        } else {
            unsigned h0 = bf16rne(o0), h1 = bf16rne(o1);
            *reinterpret_cast<ushort2*>(&ohi[oidx]) =
                make_ushort2((ushort)h0, (ushort)h1);
            *reinterpret_cast<ushort2*>(&olo[oidx]) =
                make_ushort2((ushort)bf16rne(o0 - bf16tof(h0)),
                             (ushort)bf16rne(o1 - bf16tof(h1)));
        }
    }
}

// ---------------- launch ----------------

extern "C" void kernel_launch(void* const* d_in, const int* in_sizes, int n_in,
                              void* d_out, int out_size, void* d_ws, size_t ws_size,
                              hipStream_t stream)
{
    const float* x     = (const float*)d_in[0];
    const float* Wl1   = (const float*)d_in[1];
    const float* bl1   = (const float*)d_in[2];
    const float* Wr1   = (const float*)d_in[3];
    const float* br1   = (const float*)d_in[4];
    const float* att1  = (const float*)d_in[5];
    const float* bias1 = (const float*)d_in[6];
    const float* Wl2   = (const float*)d_in[7];
    const float* bl2   = (const float*)d_in[8];
    const float* Wr2   = (const float*)d_in[9];
    const float* br2   = (const float*)d_in[10];
    const float* att2  = (const float*)d_in[11];
    const float* bias2 = (const float*)d_in[12];
    const int*   eidx  = (const int*)d_in[13];

    const int n = in_sizes[0] / 64;
    const int E = in_sizes[13] / 2;
    const int* src = eidx;
    const int* dst = eidx + E;
    const int nb = (n + 255) >> 8;        // 196 buckets

    char* ws = (char*)d_ws;
    size_t off = 0;
    auto alloc = [&](size_t bytes) -> void* {
        void* p = ws + off;
        off = (off + bytes + 255) & ~(size_t)255;
        return p;
    };
    int* rowptr   = (int*)alloc((size_t)(n + 1) * 4);
    int* ssrc     = (int*)alloc((size_t)E * 4);
    int* bcnt     = (int*)alloc((size_t)nb * 4);
    int* bbase    = (int*)alloc((size_t)(nb + 1) * 4);
    int* gwoff    = (int*)alloc((size_t)nb * 4);
    ushort* B1hi  = (ushort*)alloc((size_t)64  * 256 * 2);
    ushort* B1lo  = (ushort*)alloc((size_t)64  * 256 * 2);
    ushort* B2hi  = (ushort*)alloc((size_t)128 * 256 * 2);
    ushort* B2lo  = (ushort*)alloc((size_t)128 * 256 * 2);
    // X region: xhi1/xlo1 (layer-1 A) live first; after gemm1 consumes them,
    // agg1 overwrites the region with hhi/hlo.
    ushort* xreg  = (ushort*)alloc((size_t)n * 128 * 2 * 2);
    ushort* xhi1  = xreg;
    ushort* xlo1  = xreg + (size_t)n * 64;
    ushort* hhi   = xreg;
    ushort* hlo   = xreg + (size_t)n * 128;
    ushort* xlb   = (ushort*)alloc((size_t)n * 128 * 2);   // head-major bf16 xl
    float* xrbuf  = (float*)alloc((size_t)n * 128 * 4);
    // pairs (E * 8B = 6.8MB) aliases xlb (12.8MB): consumed by bucket_sort
    // strictly before gemm1 writes xlb.
    int2* pairs   = (int2*)xlb;
    float* outp   = (float*)d_out;

    // ---- CSR build: bucketed multisplit ----
    hipMemsetAsync(bcnt, 0, (size_t)nb * 4, stream);
    bucket_hist<<<128, 256, 0, stream>>>(dst, bcnt, E, nb);
    bucket_scan<<<1, 256, 0, stream>>>(bcnt, bbase, gwoff, rowptr, E, nb, n);
    multisplit<<<(E + TILE - 1) / TILE, 256, 0, stream>>>(src, dst, gwoff, pairs, E, nb);
    bucket_sort<<<nb, 256, 0, stream>>>(pairs, bbase, rowptr, ssrc, n);

    // ---- prep: bf16 hi/lo splits ----
    const int total4 = n * 64 / 4;
    split_x<<<(total4 + 255) / 256, 256, 0, stream>>>(x, xhi1, xlo1, total4);
    pack_W<<<(64  * 256 + 255) / 256, 256, 0, stream>>>(Wl1, Wr1, B1hi, B1lo, 64);
    pack_W<<<(128 * 256 + 255) / 256, 256, 0, stream>>>(Wl2, Wr2, B2hi, B2lo, 128);

    const dim3 ggrid((n + 63) / 64, 2);
    const int nodeblks = (n + 3) / 4;
    const int agrid = nodeblks * 4;   // 4 heads, head-major dispatch order

    // ---- layer 1 ----
    gemm_mfma<64><<<ggrid, 256, 0, stream>>>(xhi1, xlo1, B1hi, B1lo, bl1, br1,
                                             xlb, xrbuf, n);
    gat_agg<1><<<agrid, 256, 0, stream>>>(xlb, xrbuf, att1, bias1, rowptr, ssrc,
                                          nullptr, hhi, hlo, n, nodeblks);

    // ---- layer 2 ----
    gemm_mfma<128><<<ggrid, 256, 0, stream>>>(hhi, hlo, B2hi, B2lo, bl2, br2,
                                              xlb, xrbuf, n);
    gat_agg<0><<<agrid, 256, 0, stream>>>(xlb, xrbuf, att2, bias2, rowptr, ssrc,
                                          outp, nullptr, nullptr, n, nodeblks);
}

// Round 9
// 192.981 us; speedup vs baseline: 1.7683x; 1.7683x over previous
//
#include <hip/hip_runtime.h>

#define LEAKY 0.2f
#define NBSHIFT 8          // 256 nodes per bucket
#define TILE 4096          // edges per multisplit block

typedef __attribute__((ext_vector_type(8))) short  bfrag;   // 8 bf16 = 4 VGPR
typedef __attribute__((ext_vector_type(4))) float  f32x4;

__device__ __forceinline__ unsigned bf16rne(float v) {
    unsigned u = __float_as_uint(v);
    return (u + 0x7FFF + ((u >> 16) & 1)) >> 16;
}
__device__ __forceinline__ float bf16tof(unsigned b) { return __uint_as_float(b << 16); }

// pure-VALU DPP lane sums (no ds_swizzle/lgkm waits)
#define DPPADD(p, ctrl)                                                       \
    p += __int_as_float(__builtin_amdgcn_mov_dpp(__float_as_int(p), ctrl,     \
                                                 0xF, 0xF, true))
// sum over each aligned 8-lane group: xor1, xor2, then half-row mirror
__device__ __forceinline__ float rowsum8(float p) {
    DPPADD(p, 0xB1);   // quad_perm [1,0,3,2] = xor 1
    DPPADD(p, 0x4E);   // quad_perm [2,3,0,1] = xor 2
    DPPADD(p, 0x141);  // row_half_mirror    = xor 7 within 8-lane group
    return p;
}

// ---------------- CSR build: bucketed multisplit ----------------
// Edge record packed in ONE int (requires n <= 65536; here n = 50000):
//   bits [15:0] = src, [23:16] = dst & 255, [31:24] = bucket (dst >> 8)

__global__ __launch_bounds__(256) void bucket_hist(const int* __restrict__ dst,
                                                   int* __restrict__ bcnt, int E, int nb) {
    __shared__ int h[256];
    h[threadIdx.x] = 0;
    __syncthreads();
    for (int e = blockIdx.x * 256 + threadIdx.x; e < E; e += gridDim.x * 256)
        atomicAdd(&h[dst[e] >> NBSHIFT], 1);
    __syncthreads();
    int v = h[threadIdx.x];
    if (threadIdx.x < nb && v) atomicAdd(&bcnt[threadIdx.x], v);
}

__global__ __launch_bounds__(256) void bucket_scan(const int* __restrict__ bcnt,
                                                   int* __restrict__ bbase,
                                                   int* __restrict__ gwoff,
                                                   int* __restrict__ rowptr,
                                                   int E, int nb, int n) {
    __shared__ int s[256];
    const int t = threadIdx.x;
    int v = (t < nb) ? bcnt[t] : 0;
    s[t] = v;
    __syncthreads();
    for (int off = 1; off < 256; off <<= 1) {
        int a = (t >= off) ? s[t - off] : 0;
        __syncthreads();
        s[t] += a;
        __syncthreads();
    }
    int excl = s[t] - v;
    if (t < nb) { bbase[t] = excl; gwoff[t] = excl; }
    if (t == 0) { bbase[nb] = E; rowptr[n] = E; }
}

// Tile-wise multisplit: stage TILE packed edges in LDS sorted by bucket,
// reserve per-bucket global chunks, flush coalesced runs.
__global__ __launch_bounds__(256) void multisplit(const int* __restrict__ src,
                                                  const int* __restrict__ dst,
                                                  int* __restrict__ gwoff,
                                                  int* __restrict__ pairs, int E, int nb) {
    __shared__ int hist[256], lofs[256], gb[256];
    __shared__ int st[TILE];
    const int t = threadIdx.x;
    const int tile0 = blockIdx.x * TILE;
    const int tend = min(tile0 + TILE, E);
    hist[t] = 0;
    __syncthreads();
    for (int e = tile0 + t; e < tend; e += 256)
        atomicAdd(&hist[dst[e] >> NBSHIFT], 1);
    __syncthreads();
    int v = hist[t];
    lofs[t] = v;
    __syncthreads();
    for (int off = 1; off < 256; off <<= 1) {
        int a = (t >= off) ? lofs[t - off] : 0;
        __syncthreads();
        lofs[t] += a;
        __syncthreads();
    }
    int excl = lofs[t] - v;
    __syncthreads();
    lofs[t] = excl;
    if (t < nb && v > 0) gb[t] = atomicAdd(&gwoff[t], v);
    hist[t] = 0;
    __syncthreads();
    for (int e = tile0 + t; e < tend; e += 256) {
        int d = dst[e];
        int b = d >> NBSHIFT;
        int r = atomicAdd(&hist[b], 1);
        st[lofs[b] + r] = (src[e] & 0xFFFF) | ((d & 255) << 16) | (b << 24);
    }
    __syncthreads();
    const int total = tend - tile0;
    for (int i = t; i < total; i += 256) {
        int p = st[i];
        int b = ((unsigned)p) >> 24;
        pairs[gb[b] + (i - lofs[b])] = p;
    }
}

// One block per bucket: LDS counting sort over the 256-node range ->
// rowptr + ssrc (writes land in a single-block region: L2 merges lines).
__global__ __launch_bounds__(256) void bucket_sort(const int* __restrict__ pairs,
                                                   const int* __restrict__ bbase,
                                                   int* __restrict__ rowptr,
                                                   int* __restrict__ ssrc, int n) {
    __shared__ int hist[256], ofs[256];
    const int b = blockIdx.x, t = threadIdx.x;
    const int base = b << NBSHIFT;
    const int pbeg = bbase[b], pend = bbase[b + 1];
    hist[t] = 0;
    __syncthreads();
    for (int i = pbeg + t; i < pend; i += 256)
        atomicAdd(&hist[(pairs[i] >> 16) & 255], 1);
    __syncthreads();
    int v = hist[t];
    ofs[t] = v;
    __syncthreads();
    for (int off = 1; off < 256; off <<= 1) {
        int a = (t >= off) ? ofs[t - off] : 0;
        __syncthreads();
        ofs[t] += a;
        __syncthreads();
    }
    int excl = ofs[t] - v;
    __syncthreads();
    ofs[t] = excl;
    const int node = base + t;
    if (node < n) rowptr[node] = pbeg + excl;
    __syncthreads();
    for (int i = pbeg + t; i < pend; i += 256) {
        int p = pairs[i];
        int pos = atomicAdd(&ofs[(p >> 16) & 255], 1);
        ssrc[pbeg + pos] = p & 0xFFFF;
    }
}

// ---------------- prep: split x into bf16 hi/lo planes ----------------

__global__ void split_x(const float* __restrict__ x, ushort* __restrict__ xhi,
                        ushort* __restrict__ xlo, int total4) {
    int i = blockIdx.x * blockDim.x + threadIdx.x;
    if (i >= total4) return;
    float4 v = reinterpret_cast<const float4*>(x)[i];
    ushort4 h, l;
    float* vp = &v.x;
    ushort* hp = &h.x;
    ushort* lp = &l.x;
#pragma unroll
    for (int j = 0; j < 4; ++j) {
        unsigned hb = bf16rne(vp[j]);
        hp[j] = (ushort)hb;
        lp[j] = (ushort)bf16rne(vp[j] - bf16tof(hb));
    }
    reinterpret_cast<ushort4*>(xhi)[i] = h;
    reinterpret_cast<ushort4*>(xlo)[i] = l;
}

// ---------------- prep: pack [Wl|Wr] into MFMA B-fragment order ----------------
// b-frag (s = k/32, f = col/16): lane l, elem j holds W[s*32 + (l>>4)*8 + j][f*16 + (l&15)]

__global__ void pack_W(const float* __restrict__ Wl, const float* __restrict__ Wr,
                       ushort* __restrict__ Bhi, ushort* __restrict__ Blo, int K) {
    int tid = blockIdx.x * blockDim.x + threadIdx.x;
    if (tid >= K * 256) return;
    int k = tid >> 8;
    int c = tid & 255;
    float w = (c < 128) ? Wl[k * 128 + c] : Wr[k * 128 + (c - 128)];
    int s = k >> 5, kin = k & 31, kgrp = kin >> 3, j = kin & 7;
    int f = c >> 4, cin = c & 15;
    int lane = kgrp * 16 + cin;
    size_t pos = ((size_t)(s * 16 + f) * 64 + lane) * 8 + j;
    unsigned hb = bf16rne(w);
    Bhi[pos] = (ushort)hb;
    Blo[pos] = (ushort)bf16rne(w - bf16tof(hb));
}

// ---------------- MFMA GEMM: [xl|xr] = A @ [Wl|Wr] + [bl|br] ----------------
// grid = (row-tiles, 2 N-halves). Block = 4 waves, tile 64 rows x 128 cols.
// B staged in LDS (32KB -> 4 blocks/CU), read via ds_read_b128.
// Split-bf16: acc += alo*bhi + ahi*blo + ahi*bhi.
// BOTH halves now write bf16 planes: xl (gathered) and xr (streamed) --
// halves gat_agg's xr stream and gemm's own write traffic.

template<int K>
__global__ __launch_bounds__(256) void gemm_mfma(
    const ushort* __restrict__ Ahi, const ushort* __restrict__ Alo,
    const ushort* __restrict__ Bhi, const ushort* __restrict__ Blo,
    const float* __restrict__ bl, const float* __restrict__ br,
    ushort* __restrict__ xlb, ushort* __restrict__ xrb, int n)
{
    __shared__ ushort BshH[2 * 8 * 64 * 8];   // [ss][fl][lane][j] 16KB
    __shared__ ushort BshL[2 * 8 * 64 * 8];   // 16KB
    const int t = threadIdx.x;
    const int w = t >> 6;
    const int lane = t & 63;
    const int half = blockIdx.y;              // 0 -> xl cols, 1 -> xr cols
    const int r0 = blockIdx.x * 64 + w * 16;
    const int rl = lane & 15;
    const int kg = lane >> 4;
    int arow = r0 + rl; if (arow >= n) arow = 0;   // clamp loads; stores guarded

    const float4* __restrict__ gH = reinterpret_cast<const float4*>(Bhi);
    const float4* __restrict__ gL = reinterpret_cast<const float4*>(Blo);
    float4* __restrict__ sH = reinterpret_cast<float4*>(BshH);
    float4* __restrict__ sL = reinterpret_cast<float4*>(BshL);

    f32x4 acc[8];
#pragma unroll
    for (int f = 0; f < 8; ++f) acc[f] = (f32x4){0.f, 0.f, 0.f, 0.f};

#pragma unroll
    for (int sg = 0; sg < K / 64; ++sg) {
        if (sg) __syncthreads();
        // stage s = 2sg, 2sg+1 for this block's 8 col-frags
#pragma unroll
        for (int i = t; i < 1024; i += 256) {
            int ss = i >> 9, fl = (i >> 6) & 7, ln = i & 63;
            int gidx = ((2 * sg + ss) * 16 + half * 8 + fl) * 64 + ln;
            sH[i] = gH[gidx];
            sL[i] = gL[gidx];
        }
        __syncthreads();

#pragma unroll
        for (int ss = 0; ss < 2; ++ss) {
            const int s = 2 * sg + ss;
            const size_t ao = (size_t)arow * K + s * 32 + kg * 8;
            bfrag ahi = *reinterpret_cast<const bfrag*>(&Ahi[ao]);
            bfrag alo = *reinterpret_cast<const bfrag*>(&Alo[ao]);
#pragma unroll
            for (int fl = 0; fl < 8; ++fl) {
                const int lofs = ((ss * 8 + fl) * 64 + lane) * 8;
                bfrag bhi = *reinterpret_cast<const bfrag*>(&BshH[lofs]);
                bfrag blo = *reinterpret_cast<const bfrag*>(&BshL[lofs]);
                acc[fl] = __builtin_amdgcn_mfma_f32_16x16x32_bf16(alo, bhi, acc[fl], 0, 0, 0);
                acc[fl] = __builtin_amdgcn_mfma_f32_16x16x32_bf16(ahi, blo, acc[fl], 0, 0, 0);
                acc[fl] = __builtin_amdgcn_mfma_f32_16x16x32_bf16(ahi, bhi, acc[fl], 0, 0, 0);
            }
        }
    }

    // D layout: col = fl*16 + (lane&15), row = r0 + (lane>>4)*4 + j
    const int cin = lane & 15;
    const float* __restrict__ bias_ = half ? br : bl;
    ushort* __restrict__ outp = half ? xrb : xlb;
#pragma unroll
    for (int fl = 0; fl < 8; ++fl) {
        const int cc = fl * 16 + cin;
        const float bv = bias_[cc];
#pragma unroll
        for (int j = 0; j < 4; ++j) {
            const int rr = r0 + kg * 4 + j;
            if (rr < n)
                outp[(size_t)rr * 128 + cc] = (ushort)bf16rne(acc[fl][j] + bv);
        }
    }
}

// ---------------- fused per-destination GATv2 aggregation ----------------
// (round-7 structure, known-good) One node per wave, TWO EDGES PER WAVE-PASS:
// lanes 0-31 edge A, lanes 32-63 edge B. Lane owns 4 channels (uint2 = 8B
// gather, 256B/edge). Head = 8-lane group -> 3-step DPP rowsum8. Halves
// combined via shfl_xor(32). xr now bf16 (decoded once per node).

template<int OUTMODE>
__global__ __launch_bounds__(256) void gat_agg(
    const ushort* __restrict__ xlb, const ushort* __restrict__ xrb,
    const float* __restrict__ att, const float* __restrict__ bias,
    const int* __restrict__ rowptr, const int* __restrict__ ssrc,
    float* __restrict__ out, ushort* __restrict__ ohi, ushort* __restrict__ olo,
    int n)
{
    const int node = blockIdx.x * 4 + (threadIdx.x >> 6);
    if (node >= n) return;
    const int lane = threadIdx.x & 63;
    const int m = lane & 31;
    const bool hiHalf = lane >= 32;

    const uint2* __restrict__ xlu = reinterpret_cast<const uint2*>(xlb);
    const float4 a4 = reinterpret_cast<const float4*>(att)[m];
    float4 xrv;
    {
        const uint2 u = reinterpret_cast<const uint2*>(xrb)[(size_t)node * 32 + m];
        xrv.x = __uint_as_float(u.x << 16);
        xrv.y = __uint_as_float(u.x & 0xFFFF0000u);
        xrv.z = __uint_as_float(u.y << 16);
        xrv.w = __uint_as_float(u.y & 0xFFFF0000u);
    }

    float den = 0.f;
    float4 acc = make_float4(0.f, 0.f, 0.f, 0.f);

#define GATHER(sA, sB) xlu[(size_t)(hiHalf ? (sB) : (sA)) * 32 + m]
#define PAIR(u, MSK)                                                  \
    {                                                                 \
        const float x0 = __uint_as_float((u).x << 16);                \
        const float x1 = __uint_as_float((u).x & 0xFFFF0000u);        \
        const float x2 = __uint_as_float((u).y << 16);                \
        const float x3 = __uint_as_float((u).y & 0xFFFF0000u);        \
        float e0 = x0 + xrv.x, e1 = x1 + xrv.y;                       \
        float e2 = x2 + xrv.z, e3 = x3 + xrv.w;                       \
        e0 = fmaxf(e0, LEAKY * e0);                                   \
        e1 = fmaxf(e1, LEAKY * e1);                                   \
        e2 = fmaxf(e2, LEAKY * e2);                                   \
        e3 = fmaxf(e3, LEAKY * e3);                                   \
        float p = e0 * a4.x + e1 * a4.y + e2 * a4.z + e3 * a4.w;      \
        p = rowsum8(p);                                               \
        float ex = __expf(p) MSK;                                     \
        den += ex;                                                    \
        acc.x += ex * x0; acc.y += ex * x1;                           \
        acc.z += ex * x2; acc.w += ex * x3;                           \
    }

    int i = rowptr[node];
    const int end = rowptr[node + 1];

    // pass 0: self-loop (half A) + first real edge (half B, if any)
    {
        const bool vB = i < end;
        const int sB = vB ? ssrc[i] : node;
        uint2 u = GATHER(node, sB);
        const float msk = (hiHalf && !vB) ? 0.f : 1.f;
        PAIR(u, * msk);
        if (vB) ++i;
    }

    for (; i + 8 <= end; i += 8) {
        int s0 = ssrc[i],     s1 = ssrc[i + 1], s2 = ssrc[i + 2], s3 = ssrc[i + 3];
        int s4 = ssrc[i + 4], s5 = ssrc[i + 5], s6 = ssrc[i + 6], s7 = ssrc[i + 7];
        uint2 u0 = GATHER(s0, s1);
        uint2 u1 = GATHER(s2, s3);
        uint2 u2 = GATHER(s4, s5);
        uint2 u3 = GATHER(s6, s7);
        PAIR(u0, );
        PAIR(u1, );
        PAIR(u2, );
        PAIR(u3, );
    }
    for (; i + 2 <= end; i += 2) {
        int s0 = ssrc[i], s1 = ssrc[i + 1];
        uint2 u = GATHER(s0, s1);
        PAIR(u, );
    }
    if (i < end) {
        int s0 = ssrc[i];
        uint2 u = GATHER(s0, s0);
        const float msk = hiHalf ? 0.f : 1.f;
        PAIR(u, * msk);
    }
#undef PAIR
#undef GATHER

    // combine the two halves
    den   += __shfl_xor(den,   32);
    acc.x += __shfl_xor(acc.x, 32);
    acc.y += __shfl_xor(acc.y, 32);
    acc.z += __shfl_xor(acc.z, 32);
    acc.w += __shfl_xor(acc.w, 32);

    if (!hiHalf) {
        const float4 b4 = reinterpret_cast<const float4*>(bias)[m];
        const float r = 1.f / den;
        const float o0 = fmaxf(acc.x * r + b4.x, 0.f);
        const float o1 = fmaxf(acc.y * r + b4.y, 0.f);
        const float o2 = fmaxf(acc.z * r + b4.z, 0.f);
        const float o3 = fmaxf(acc.w * r + b4.w, 0.f);
        if (OUTMODE == 0) {
            reinterpret_cast<float4*>(out)[(size_t)node * 32 + m] =
                make_float4(o0, o1, o2, o3);
        } else {
            unsigned h0 = bf16rne(o0), h1 = bf16rne(o1);
            unsigned h2 = bf16rne(o2), h3 = bf16rne(o3);
            ushort4 hv = make_ushort4((ushort)h0, (ushort)h1, (ushort)h2, (ushort)h3);
            ushort4 lv = make_ushort4((ushort)bf16rne(o0 - bf16tof(h0)),
                                      (ushort)bf16rne(o1 - bf16tof(h1)),
                                      (ushort)bf16rne(o2 - bf16tof(h2)),
                                      (ushort)bf16rne(o3 - bf16tof(h3)));
            reinterpret_cast<ushort4*>(ohi)[(size_t)node * 32 + m] = hv;
            reinterpret_cast<ushort4*>(olo)[(size_t)node * 32 + m] = lv;
        }
    }
}

// ---------------- launch ----------------

extern "C" void kernel_launch(void* const* d_in, const int* in_sizes, int n_in,
                              void* d_out, int out_size, void* d_ws, size_t ws_size,
                              hipStream_t stream)
{
    const float* x     = (const float*)d_in[0];
    const float* Wl1   = (const float*)d_in[1];
    const float* bl1   = (const float*)d_in[2];
    const float* Wr1   = (const float*)d_in[3];
    const float* br1   = (const float*)d_in[4];
    const float* att1  = (const float*)d_in[5];
    const float* bias1 = (const float*)d_in[6];
    const float* Wl2   = (const float*)d_in[7];
    const float* bl2   = (const float*)d_in[8];
    const float* Wr2   = (const float*)d_in[9];
    const float* br2   = (const float*)d_in[10];
    const float* att2  = (const float*)d_in[11];
    const float* bias2 = (const float*)d_in[12];
    const int*   eidx  = (const int*)d_in[13];

    const int n = in_sizes[0] / 64;
    const int E = in_sizes[13] / 2;
    const int* src = eidx;
    const int* dst = eidx + E;
    const int nb = (n + 255) >> 8;        // 196 buckets

    char* ws = (char*)d_ws;
    size_t off = 0;
    auto alloc = [&](size_t bytes) -> void* {
        void* p = ws + off;
        off = (off + bytes + 255) & ~(size_t)255;
        return p;
    };
    int* rowptr   = (int*)alloc((size_t)(n + 1) * 4);
    int* ssrc     = (int*)alloc((size_t)E * 4);
    int* bcnt     = (int*)alloc((size_t)nb * 4);
    int* bbase    = (int*)alloc((size_t)(nb + 1) * 4);
    int* gwoff    = (int*)alloc((size_t)nb * 4);
    ushort* B1hi  = (ushort*)alloc((size_t)64  * 256 * 2);
    ushort* B1lo  = (ushort*)alloc((size_t)64  * 256 * 2);
    ushort* B2hi  = (ushort*)alloc((size_t)128 * 256 * 2);
    ushort* B2lo  = (ushort*)alloc((size_t)128 * 256 * 2);
    // X region: xhi1/xlo1 (layer-1 A) live first; after gemm1 consumes them,
    // agg1 overwrites the region with hhi/hlo.
    ushort* xreg  = (ushort*)alloc((size_t)n * 128 * 2 * 2);
    ushort* xhi1  = xreg;
    ushort* xlo1  = xreg + (size_t)n * 64;
    ushort* hhi   = xreg;
    ushort* hlo   = xreg + (size_t)n * 128;
    ushort* xlb   = (ushort*)alloc((size_t)n * 128 * 2);   // bf16 xl plane
    ushort* xrb   = (ushort*)alloc((size_t)n * 128 * 2);   // bf16 xr plane
    // packed pairs (E * 4B = 3.4MB) alias xlb (12.8MB): consumed by
    // bucket_sort strictly before gemm1 writes xlb.
    int* pairs    = (int*)xlb;
    float* outp   = (float*)d_out;

    // ---- CSR build: bucketed multisplit ----
    hipMemsetAsync(bcnt, 0, (size_t)nb * 4, stream);
    bucket_hist<<<128, 256, 0, stream>>>(dst, bcnt, E, nb);
    bucket_scan<<<1, 256, 0, stream>>>(bcnt, bbase, gwoff, rowptr, E, nb, n);
    multisplit<<<(E + TILE - 1) / TILE, 256, 0, stream>>>(src, dst, gwoff, pairs, E, nb);
    bucket_sort<<<nb, 256, 0, stream>>>(pairs, bbase, rowptr, ssrc, n);

    // ---- prep: bf16 hi/lo splits ----
    const int total4 = n * 64 / 4;
    split_x<<<(total4 + 255) / 256, 256, 0, stream>>>(x, xhi1, xlo1, total4);
    pack_W<<<(64  * 256 + 255) / 256, 256, 0, stream>>>(Wl1, Wr1, B1hi, B1lo, 64);
    pack_W<<<(128 * 256 + 255) / 256, 256, 0, stream>>>(Wl2, Wr2, B2hi, B2lo, 128);

    const dim3 ggrid((n + 63) / 64, 2);

    // ---- layer 1 ----
    gemm_mfma<64><<<ggrid, 256, 0, stream>>>(xhi1, xlo1, B1hi, B1lo, bl1, br1,
                                             xlb, xrb, n);
    gat_agg<1><<<(n + 3) / 4, 256, 0, stream>>>(xlb, xrb, att1, bias1, rowptr, ssrc,
                                                nullptr, hhi, hlo, n);

    // ---- layer 2 ----
    gemm_mfma<128><<<ggrid, 256, 0, stream>>>(hhi, hlo, B2hi, B2lo, bl2, br2,
                                              xlb, xrb, n);
    gat_agg<0><<<(n + 3) / 4, 256, 0, stream>>>(xlb, xrb, att2, bias2, rowptr, ssrc,
                                                outp, nullptr, nullptr, n);
}